// Round 3
// baseline (1179.876 us; speedup 1.0000x reference)
//
#include <hip/hip_runtime.h>

// ---------- types ----------
typedef short s16x8 __attribute__((ext_vector_type(8)));   // 8 bf16 (4 VGPRs)
typedef float f32x4 __attribute__((ext_vector_type(4)));

static __device__ __forceinline__ unsigned short f2bf(float f) {
  unsigned u = __builtin_bit_cast(unsigned, f);
  unsigned r = (u + 0x7FFFu + ((u >> 16) & 1u)) >> 16;   // RNE; inputs finite
  return (unsigned short)r;
}

#define KD 512
// B = 16, T = 512, C = 19, E = 512, H = 8, HD = 64
// groups = B*T = 8192, rows = groups*19 = 155648

// ---------- kernel: convert weights fp32 -> bf16, rows 0..511 = w_q, 512..1023 = w_k ----------
__global__ void k_convw(const float* __restrict__ wq, const float* __restrict__ wk,
                        unsigned short* __restrict__ Wb) {
  int idx = blockIdx.x * 256 + threadIdx.x;   // 65536 threads, 8 elems each
  int f  = idx >> 6;
  int c8 = (idx & 63) << 3;
  const float* src = (f < 512) ? (wq + f * 512 + c8) : (wk + (f - 512) * 512 + c8);
  float4 v0 = *(const float4*)(src);
  float4 v1 = *(const float4*)(src + 4);
  s16x8 o;
  o[0] = (short)f2bf(v0.x); o[1] = (short)f2bf(v0.y); o[2] = (short)f2bf(v0.z); o[3] = (short)f2bf(v0.w);
  o[4] = (short)f2bf(v1.x); o[5] = (short)f2bf(v1.y); o[6] = (short)f2bf(v1.z); o[7] = (short)f2bf(v1.w);
  *(s16x8*)(Wb + f * 512 + c8) = o;
}

// ---------- kernel: QK = eeg @ [Wq^T | Wk^T] + bias, bf16 out ----------
// v3: A panel (64 rows x 512 K) stored in LDS in MFMA *fragment layout*:
//   frag f = ks*4 + m (ks = k>>5, m = row>>4), within-frag lane = (row&15) + 16*((k>>3)&3),
//   addr = f*1024 + lane*16.  Main-loop ds_read_b128 is lane-linear -> zero bank conflicts.
// B fragments read directly from global (W = 1 MB, L2-resident) with explicit depth-2
// register rotation so loads issue ~2 K-steps ahead of use. No main-loop barriers.
__global__ __launch_bounds__(512, 4)
void k_gemm(const float* __restrict__ A, const unsigned short* __restrict__ Wb,
            const float* __restrict__ bq, const float* __restrict__ bk,
            unsigned short* __restrict__ QK, long grow0) {
  __shared__ unsigned short Ap[64 * 512];      // 65,536 B, fragment layout

  const int tid  = threadIdx.x;
  const int lane = tid & 63;
  const int wid  = tid >> 6;                   // 0..7
  const int rlo  = lane & 15;
  const int rhi  = lane >> 4;
  const long arow0 = grow0 + (long)blockIdx.x * 64;
  char* lds = (char*)Ap;

  // ---- stage A: fp32 -> bf16 -> fragment-layout LDS ----
  // lane mapping keeps global reads in 256B segments and LDS write banks spread.
#pragma unroll
  for (int r = 0; r < 8; ++r) {
    int row = r * 8 + (lane >> 3);             // 0..63
    int kc  = wid * 8 + (lane & 7);            // 16B k-chunk (8 bf16), 0..63
    const float* ap = A + (arow0 + row) * KD + kc * 8;
    float4 v0 = *(const float4*)(ap);
    float4 v1 = *(const float4*)(ap + 4);
    s16x8 o;
    o[0]=(short)f2bf(v0.x); o[1]=(short)f2bf(v0.y); o[2]=(short)f2bf(v0.z); o[3]=(short)f2bf(v0.w);
    o[4]=(short)f2bf(v1.x); o[5]=(short)f2bf(v1.y); o[6]=(short)f2bf(v1.z); o[7]=(short)f2bf(v1.w);
    int f  = (kc >> 2) * 4 + (row >> 4);       // frag index = ks*4 + m
    int lp = (row & 15) + 16 * (kc & 3);       // lane within frag
    *(s16x8*)(lds + f * 1024 + lp * 16) = o;
  }
  __syncthreads();

  // ---- main: wave owns 64 rows x 32 cols per chunk; 4 chunks; no barriers ----
#pragma unroll 1
  for (int cc = 0; cc < 4; ++cc) {
    const int c0 = wid * 128 + cc * 32;
    f32x4 acc[4][2] = {};

    const unsigned short* bp0 = Wb + (long)(c0 + rlo) * KD + rhi * 8;
    const unsigned short* bp1 = Wb + (long)(c0 + 16 + rlo) * KD + rhi * 8;

    // depth-2 prefetch rotation (indices compile-time under full unroll)
    s16x8 bbuf[2][2];
    bbuf[0][0] = *(const s16x8*)(bp0);           bbuf[0][1] = *(const s16x8*)(bp1);
    bbuf[1][0] = *(const s16x8*)(bp0 + 32);      bbuf[1][1] = *(const s16x8*)(bp1 + 32);

#pragma unroll
    for (int ks = 0; ks < 16; ++ks) {
      s16x8 b0 = bbuf[ks & 1][0];
      s16x8 b1 = bbuf[ks & 1][1];
      if (ks < 14) {
        bbuf[ks & 1][0] = *(const s16x8*)(bp0 + (ks + 2) * 32);
        bbuf[ks & 1][1] = *(const s16x8*)(bp1 + (ks + 2) * 32);
      }
      s16x8 af[4];
#pragma unroll
      for (int m = 0; m < 4; ++m)
        af[m] = *(const s16x8*)(lds + ((ks * 4 + m) << 10) + lane * 16);
#pragma unroll
      for (int m = 0; m < 4; ++m) {
        acc[m][0] = __builtin_amdgcn_mfma_f32_16x16x32_bf16(af[m], b0, acc[m][0], 0, 0, 0);
        acc[m][1] = __builtin_amdgcn_mfma_f32_16x16x32_bf16(af[m], b1, acc[m][1], 0, 0, 0);
      }
    }

    // ---- epilogue for this col-chunk ----
#pragma unroll
    for (int nb = 0; nb < 2; ++nb) {
      int colg = c0 + nb * 16 + rlo;
      float bias = (colg < 512) ? bq[colg] : bk[colg - 512];
#pragma unroll
      for (int m = 0; m < 4; ++m) {
        long rl = (long)blockIdx.x * 64 + m * 16 + (rhi << 2);
#pragma unroll
        for (int j = 0; j < 4; ++j)
          QK[(rl + j) * 1024 + colg] = f2bf(acc[m][nb][j] + bias);
      }
    }
  }
}

// ---------- kernel: per-group attention -> atomic strength accumulation ----------
__global__ __launch_bounds__(256, 3)
void k_attn(const unsigned short* __restrict__ QK, float* __restrict__ acc, int g0) {
  __shared__ unsigned short Qs[19][1032];   // 39,216 B (padded stride: 2-way banks)
  __shared__ float Sc[8][19][20];           // 12,160 B
  __shared__ float red[256];

  const int tid  = threadIdx.x;
  const int lane = tid & 63;
  const int wid  = tid >> 6;
  const long gl  = blockIdx.x;

  // stage this group's Q|K rows (19 x 1024 bf16)
  const unsigned short* src = QK + gl * 19 * 1024;
  for (int c = tid; c < 2432; c += 256) {
    int row = c >> 7, c8 = (c & 127) << 3;
    *(s16x8*)&Qs[row][c8] = *(const s16x8*)(src + row * 1024 + c8);
  }
  __syncthreads();

  const int rlo = lane & 15, rhi = lane >> 4;
  const s16x8 z8 = {};
  // scores: wave wid handles heads 2*wid, 2*wid+1
#pragma unroll
  for (int hh = 0; hh < 2; ++hh) {
    const int h = wid * 2 + hh;
    f32x4 s[2][2] = {};
#pragma unroll
    for (int ks = 0; ks < 2; ++ks) {
      s16x8 qa[2], kb[2];
#pragma unroll
      for (int mi = 0; mi < 2; ++mi) {
        int r = mi * 16 + rlo;
        qa[mi] = (r < 19) ? *(const s16x8*)&Qs[r][h * 64 + ks * 32 + rhi * 8] : z8;
        kb[mi] = (r < 19) ? *(const s16x8*)&Qs[r][512 + h * 64 + ks * 32 + rhi * 8] : z8;
      }
#pragma unroll
      for (int mi = 0; mi < 2; ++mi)
#pragma unroll
        for (int nj = 0; nj < 2; ++nj)
          s[mi][nj] = __builtin_amdgcn_mfma_f32_16x16x32_bf16(qa[mi], kb[nj], s[mi][nj], 0, 0, 0);
    }
#pragma unroll
    for (int mi = 0; mi < 2; ++mi)
#pragma unroll
      for (int nj = 0; nj < 2; ++nj)
#pragma unroll
        for (int j = 0; j < 4; ++j) {
          int r = mi * 16 + rhi * 4 + j, c = nj * 16 + rlo;
          if (r < 19 && c < 19) Sc[h][r][c] = s[mi][nj][j] * 0.125f;  // 1/sqrt(64)
        }
  }
  __syncthreads();

  // row softmax: thread r<152 -> (h, i); partial = sum_{j>i} p_j
  float p = 0.f;
  if (tid < 152) {
    int h = tid / 19, i = tid - h * 19;
    float sv[19];
    float mx = -1e30f;
#pragma unroll
    for (int j = 0; j < 19; ++j) { sv[j] = Sc[h][i][j]; mx = fmaxf(mx, sv[j]); }
    float sum = 0.f, up = 0.f;
#pragma unroll
    for (int j = 0; j < 19; ++j) {
      float e = __expf(sv[j] - mx);
      sum += e;
      if (j > i) up += e;
    }
    p = up / sum;
  }
  red[tid] = p;
  __syncthreads();
  for (int off = 128; off > 0; off >>= 1) {
    if (tid < off) red[tid] += red[tid + off];
    __syncthreads();
  }
  if (tid == 0) {
    int b = (g0 + (int)blockIdx.x) >> 9;    // T = 512
    atomicAdd(&acc[b], red[0]);
  }
}

// ---------- kernel: finalize out[b] = clip(acc[b] / (8*171*512), 0, 1) ----------
__global__ void k_fin(const float* __restrict__ acc, float* __restrict__ out) {
  int t = threadIdx.x;
  if (t < 16) {
    float v = acc[t] * (1.0f / 700416.0f);
    out[t] = fminf(1.0f, fmaxf(0.0f, v));
  }
}

// ---------- host ----------
extern "C" void kernel_launch(void* const* d_in, const int* in_sizes, int n_in,
                              void* d_out, int out_size, void* d_ws, size_t ws_size,
                              hipStream_t stream) {
  const float* eeg = (const float*)d_in[0];
  const float* wq  = (const float*)d_in[1];
  const float* wk  = (const float*)d_in[2];
  const float* bq  = (const float*)d_in[3];
  const float* bk  = (const float*)d_in[4];
  float* out = (float*)d_out;

  char* ws = (char*)d_ws;
  unsigned short* Wb = (unsigned short*)ws;              // 1 MiB bf16 weights [1024][512]
  float* acc = (float*)(ws + (1 << 20));                 // 64 B accumulators
  unsigned short* QK = (unsigned short*)(ws + (1 << 20) + 256);

  // chunk groups in units of 128 (128 groups = 2432 rows = 38 blocks of 64 rows)
  const long perChunkBytes = 128L * 19 * 1024 * 2;       // 4,980,736 B per 128 groups
  long avail = (long)ws_size - (1 << 20) - 256;
  long cap = avail / perChunkBytes;
  if (cap < 1) cap = 1;
  if (cap > 64) cap = 64;                                 // 64*128 = 8192 groups = everything
  const int chunk_groups = (int)cap * 128;

  hipMemsetAsync(acc, 0, 64, stream);
  k_convw<<<256, 256, 0, stream>>>(wq, wk, Wb);

  for (int g0 = 0; g0 < 8192; g0 += chunk_groups) {
    int cg = 8192 - g0; if (cg > chunk_groups) cg = chunk_groups;
    int nM = (cg * 19) / 64;                              // exact (cg multiple of 128)
    k_gemm<<<nM, 512, 0, stream>>>(eeg, Wb, bq, bk, QK, (long)g0 * 19);
    k_attn<<<cg, 256, 0, stream>>>(QK, acc, g0);
  }
  k_fin<<<1, 64, 0, stream>>>(acc, out);
}

// Round 4
// 508.981 us; speedup vs baseline: 2.3181x; 2.3181x over previous
//
#include <hip/hip_runtime.h>

// ---------- types ----------
typedef short s16x8 __attribute__((ext_vector_type(8)));   // 8 bf16 (4 VGPRs)
typedef float f32x4 __attribute__((ext_vector_type(4)));

static __device__ __forceinline__ unsigned short f2bf(float f) {
  unsigned u = __builtin_bit_cast(unsigned, f);
  unsigned r = (u + 0x7FFFu + ((u >> 16) & 1u)) >> 16;   // RNE; inputs finite
  return (unsigned short)r;
}

#define KD 512
// B = 16, T = 512, C = 19, E = 512, H = 8, HD = 64
// groups = B*T = 8192, rows = groups*19 = 155648

// ---------- kernel: convert weights fp32 -> bf16, rows 0..511 = w_q, 512..1023 = w_k ----------
__global__ void k_convw(const float* __restrict__ wq, const float* __restrict__ wk,
                        unsigned short* __restrict__ Wb) {
  int idx = blockIdx.x * 256 + threadIdx.x;   // 65536 threads, 8 elems each
  int f  = idx >> 6;
  int c8 = (idx & 63) << 3;
  const float* src = (f < 512) ? (wq + f * 512 + c8) : (wk + (f - 512) * 512 + c8);
  float4 v0 = *(const float4*)(src);
  float4 v1 = *(const float4*)(src + 4);
  s16x8 o;
  o[0] = (short)f2bf(v0.x); o[1] = (short)f2bf(v0.y); o[2] = (short)f2bf(v0.z); o[3] = (short)f2bf(v0.w);
  o[4] = (short)f2bf(v1.x); o[5] = (short)f2bf(v1.y); o[6] = (short)f2bf(v1.z); o[7] = (short)f2bf(v1.w);
  *(s16x8*)(Wb + f * 512 + c8) = o;
}

// ---------- kernel: QK = eeg @ [Wq^T | Wk^T] + bias, bf16 out ----------
// v4 = v2 skeleton + two fixes:
//  (a) A panel in MFMA fragment layout (ds_read_b128 at lane*16: contiguous,
//      conflict-free by construction).
//  (b) B direct from L2-resident W (v2-proven to hit cache) with a depth-1
//      software pipeline held in NAMED registers (no runtime-indexed arrays ->
//      cannot be demoted to scratch; R2's regression was scratch spill).
// 512 threads, 64 KB LDS -> 2 blocks/CU = 4 waves/SIMD. No main-loop barriers.
__global__ __launch_bounds__(512, 4)
void k_gemm(const float* __restrict__ A, const unsigned short* __restrict__ Wb,
            const float* __restrict__ bq, const float* __restrict__ bk,
            unsigned short* __restrict__ QK, long grow0) {
  __shared__ unsigned short Ap[64 * 512];      // 65,536 B, fragment layout

  const int tid  = threadIdx.x;
  const int lane = tid & 63;
  const int wid  = tid >> 6;                   // 0..7
  const int rlo  = lane & 15;
  const int rhi  = lane >> 4;
  const long arow0 = grow0 + (long)blockIdx.x * 64;
  char* lds = (char*)Ap;

  // ---- stage A: fp32 -> bf16 -> fragment-layout LDS ----
  // frag f = ks*4 + m (ks = k>>5, m = row>>4); within-frag lane = (row&15) + 16*((k>>3)&3)
#pragma unroll
  for (int r = 0; r < 8; ++r) {
    int row = r * 8 + (lane >> 3);             // 0..63
    int kc  = wid * 8 + (lane & 7);            // 16B k-chunk (8 bf16), 0..63
    const float* ap = A + (arow0 + row) * KD + kc * 8;
    float4 v0 = *(const float4*)(ap);
    float4 v1 = *(const float4*)(ap + 4);
    s16x8 o;
    o[0]=(short)f2bf(v0.x); o[1]=(short)f2bf(v0.y); o[2]=(short)f2bf(v0.z); o[3]=(short)f2bf(v0.w);
    o[4]=(short)f2bf(v1.x); o[5]=(short)f2bf(v1.y); o[6]=(short)f2bf(v1.z); o[7]=(short)f2bf(v1.w);
    int f  = (kc >> 2) * 4 + (row >> 4);       // frag index
    int lp = (row & 15) + 16 * (kc & 3);       // lane within frag
    *(s16x8*)(lds + f * 1024 + lp * 16) = o;
  }
  __syncthreads();

  // ---- main: wave owns 64 rows x 32 cols per chunk; 4 chunks; no barriers ----
#pragma unroll 1
  for (int cc = 0; cc < 4; ++cc) {
    const int c0 = wid * 128 + cc * 32;
    f32x4 acc[4][2] = {};   // static indices only (full unroll below)

    const unsigned short* bp0 = Wb + (long)(c0 + rlo) * KD + rhi * 8;
    const unsigned short* bp1 = bp0 + 16 * KD;

    // depth-1 pipeline in NAMED regs
    s16x8 cb0 = *(const s16x8*)(bp0);
    s16x8 cb1 = *(const s16x8*)(bp1);

#pragma unroll 1
    for (int ks2 = 0; ks2 < 8; ++ks2) {
      const int ks = ks2 * 2;
      // prefetch B for ks+1
      s16x8 pb0 = *(const s16x8*)(bp0 + (ks + 1) * 32);
      s16x8 pb1 = *(const s16x8*)(bp1 + (ks + 1) * 32);
      // A frags + MFMA for ks (uses cb0/cb1)
      {
        s16x8 a0 = *(const s16x8*)(lds + ((ks * 4 + 0) << 10) + lane * 16);
        s16x8 a1 = *(const s16x8*)(lds + ((ks * 4 + 1) << 10) + lane * 16);
        s16x8 a2 = *(const s16x8*)(lds + ((ks * 4 + 2) << 10) + lane * 16);
        s16x8 a3 = *(const s16x8*)(lds + ((ks * 4 + 3) << 10) + lane * 16);
        acc[0][0] = __builtin_amdgcn_mfma_f32_16x16x32_bf16(a0, cb0, acc[0][0], 0, 0, 0);
        acc[0][1] = __builtin_amdgcn_mfma_f32_16x16x32_bf16(a0, cb1, acc[0][1], 0, 0, 0);
        acc[1][0] = __builtin_amdgcn_mfma_f32_16x16x32_bf16(a1, cb0, acc[1][0], 0, 0, 0);
        acc[1][1] = __builtin_amdgcn_mfma_f32_16x16x32_bf16(a1, cb1, acc[1][1], 0, 0, 0);
        acc[2][0] = __builtin_amdgcn_mfma_f32_16x16x32_bf16(a2, cb0, acc[2][0], 0, 0, 0);
        acc[2][1] = __builtin_amdgcn_mfma_f32_16x16x32_bf16(a2, cb1, acc[2][1], 0, 0, 0);
        acc[3][0] = __builtin_amdgcn_mfma_f32_16x16x32_bf16(a3, cb0, acc[3][0], 0, 0, 0);
        acc[3][1] = __builtin_amdgcn_mfma_f32_16x16x32_bf16(a3, cb1, acc[3][1], 0, 0, 0);
      }
      // load B for ks+2 (next iteration's current)
      if (ks2 < 7) {
        cb0 = *(const s16x8*)(bp0 + (ks + 2) * 32);
        cb1 = *(const s16x8*)(bp1 + (ks + 2) * 32);
      }
      // A frags + MFMA for ks+1 (uses pb0/pb1)
      {
        s16x8 a0 = *(const s16x8*)(lds + (((ks + 1) * 4 + 0) << 10) + lane * 16);
        s16x8 a1 = *(const s16x8*)(lds + (((ks + 1) * 4 + 1) << 10) + lane * 16);
        s16x8 a2 = *(const s16x8*)(lds + (((ks + 1) * 4 + 2) << 10) + lane * 16);
        s16x8 a3 = *(const s16x8*)(lds + (((ks + 1) * 4 + 3) << 10) + lane * 16);
        acc[0][0] = __builtin_amdgcn_mfma_f32_16x16x32_bf16(a0, pb0, acc[0][0], 0, 0, 0);
        acc[0][1] = __builtin_amdgcn_mfma_f32_16x16x32_bf16(a0, pb1, acc[0][1], 0, 0, 0);
        acc[1][0] = __builtin_amdgcn_mfma_f32_16x16x32_bf16(a1, pb0, acc[1][0], 0, 0, 0);
        acc[1][1] = __builtin_amdgcn_mfma_f32_16x16x32_bf16(a1, pb1, acc[1][1], 0, 0, 0);
        acc[2][0] = __builtin_amdgcn_mfma_f32_16x16x32_bf16(a2, pb0, acc[2][0], 0, 0, 0);
        acc[2][1] = __builtin_amdgcn_mfma_f32_16x16x32_bf16(a2, pb1, acc[2][1], 0, 0, 0);
        acc[3][0] = __builtin_amdgcn_mfma_f32_16x16x32_bf16(a3, pb0, acc[3][0], 0, 0, 0);
        acc[3][1] = __builtin_amdgcn_mfma_f32_16x16x32_bf16(a3, pb1, acc[3][1], 0, 0, 0);
      }
    }

    // ---- epilogue for this col-chunk ----
#pragma unroll
    for (int nb = 0; nb < 2; ++nb) {
      int colg = c0 + nb * 16 + rlo;
      float bias = (colg < 512) ? bq[colg] : bk[colg - 512];
#pragma unroll
      for (int m = 0; m < 4; ++m) {
        long rl = (long)blockIdx.x * 64 + m * 16 + (rhi << 2);
#pragma unroll
        for (int j = 0; j < 4; ++j)
          QK[(rl + j) * 1024 + colg] = f2bf(acc[m][nb][j] + bias);
      }
    }
  }
}

// ---------- kernel: per-group attention -> atomic strength accumulation ----------
__global__ __launch_bounds__(256, 3)
void k_attn(const unsigned short* __restrict__ QK, float* __restrict__ acc, int g0) {
  __shared__ unsigned short Qs[19][1032];   // 39,216 B (padded stride: 2-way banks)
  __shared__ float Sc[8][19][20];           // 12,160 B
  __shared__ float red[256];

  const int tid  = threadIdx.x;
  const int lane = tid & 63;
  const int wid  = tid >> 6;
  const long gl  = blockIdx.x;

  // stage this group's Q|K rows (19 x 1024 bf16)
  const unsigned short* src = QK + gl * 19 * 1024;
  for (int c = tid; c < 2432; c += 256) {
    int row = c >> 7, c8 = (c & 127) << 3;
    *(s16x8*)&Qs[row][c8] = *(const s16x8*)(src + row * 1024 + c8);
  }
  __syncthreads();

  const int rlo = lane & 15, rhi = lane >> 4;
  const s16x8 z8 = {};
  // scores: wave wid handles heads 2*wid, 2*wid+1
#pragma unroll
  for (int hh = 0; hh < 2; ++hh) {
    const int h = wid * 2 + hh;
    f32x4 s[2][2] = {};
#pragma unroll
    for (int ks = 0; ks < 2; ++ks) {
      s16x8 qa[2], kb[2];
#pragma unroll
      for (int mi = 0; mi < 2; ++mi) {
        int r = mi * 16 + rlo;
        qa[mi] = (r < 19) ? *(const s16x8*)&Qs[r][h * 64 + ks * 32 + rhi * 8] : z8;
        kb[mi] = (r < 19) ? *(const s16x8*)&Qs[r][512 + h * 64 + ks * 32 + rhi * 8] : z8;
      }
#pragma unroll
      for (int mi = 0; mi < 2; ++mi)
#pragma unroll
        for (int nj = 0; nj < 2; ++nj)
          s[mi][nj] = __builtin_amdgcn_mfma_f32_16x16x32_bf16(qa[mi], kb[nj], s[mi][nj], 0, 0, 0);
    }
#pragma unroll
    for (int mi = 0; mi < 2; ++mi)
#pragma unroll
      for (int nj = 0; nj < 2; ++nj)
#pragma unroll
        for (int j = 0; j < 4; ++j) {
          int r = mi * 16 + rhi * 4 + j, c = nj * 16 + rlo;
          if (r < 19 && c < 19) Sc[h][r][c] = s[mi][nj][j] * 0.125f;  // 1/sqrt(64)
        }
  }
  __syncthreads();

  // row softmax: thread r<152 -> (h, i); partial = sum_{j>i} p_j
  float p = 0.f;
  if (tid < 152) {
    int h = tid / 19, i = tid - h * 19;
    float sv[19];
    float mx = -1e30f;
#pragma unroll
    for (int j = 0; j < 19; ++j) { sv[j] = Sc[h][i][j]; mx = fmaxf(mx, sv[j]); }
    float sum = 0.f, up = 0.f;
#pragma unroll
    for (int j = 0; j < 19; ++j) {
      float e = __expf(sv[j] - mx);
      sum += e;
      if (j > i) up += e;
    }
    p = up / sum;
  }
  red[tid] = p;
  __syncthreads();
  for (int off = 128; off > 0; off >>= 1) {
    if (tid < off) red[tid] += red[tid + off];
    __syncthreads();
  }
  if (tid == 0) {
    int b = (g0 + (int)blockIdx.x) >> 9;    // T = 512
    atomicAdd(&acc[b], red[0]);
  }
}

// ---------- kernel: finalize out[b] = clip(acc[b] / (8*171*512), 0, 1) ----------
__global__ void k_fin(const float* __restrict__ acc, float* __restrict__ out) {
  int t = threadIdx.x;
  if (t < 16) {
    float v = acc[t] * (1.0f / 700416.0f);
    out[t] = fminf(1.0f, fmaxf(0.0f, v));
  }
}

// ---------- host ----------
extern "C" void kernel_launch(void* const* d_in, const int* in_sizes, int n_in,
                              void* d_out, int out_size, void* d_ws, size_t ws_size,
                              hipStream_t stream) {
  const float* eeg = (const float*)d_in[0];
  const float* wq  = (const float*)d_in[1];
  const float* wk  = (const float*)d_in[2];
  const float* bq  = (const float*)d_in[3];
  const float* bk  = (const float*)d_in[4];
  float* out = (float*)d_out;

  char* ws = (char*)d_ws;
  unsigned short* Wb = (unsigned short*)ws;              // 1 MiB bf16 weights [1024][512]
  float* acc = (float*)(ws + (1 << 20));                 // 64 B accumulators
  unsigned short* QK = (unsigned short*)(ws + (1 << 20) + 256);

  // chunk groups in units of 128 (128 groups = 2432 rows = 38 blocks of 64 rows)
  const long perChunkBytes = 128L * 19 * 1024 * 2;       // 4,980,736 B per 128 groups
  long avail = (long)ws_size - (1 << 20) - 256;
  long cap = avail / perChunkBytes;
  if (cap < 1) cap = 1;
  if (cap > 64) cap = 64;                                 // 64*128 = 8192 groups = everything
  const int chunk_groups = (int)cap * 128;

  hipMemsetAsync(acc, 0, 64, stream);
  k_convw<<<256, 256, 0, stream>>>(wq, wk, Wb);

  for (int g0 = 0; g0 < 8192; g0 += chunk_groups) {
    int cg = 8192 - g0; if (cg > chunk_groups) cg = chunk_groups;
    int nM = (cg * 19) / 64;                              // exact (cg multiple of 128)
    k_gemm<<<nM, 512, 0, stream>>>(eeg, Wb, bq, bk, QK, (long)g0 * 19);
    k_attn<<<cg, 256, 0, stream>>>(QK, acc, g0);
  }
  k_fin<<<1, 64, 0, stream>>>(acc, out);
}